// Round 9
// baseline (653.687 us; speedup 1.0000x reference)
//
#include <hip/hip_runtime.h>
#include <cstdint>

typedef __attribute__((ext_vector_type(8))) short s8v;   // 8 x bf16 (as i16)
typedef __attribute__((ext_vector_type(4))) float f4v;   // MFMA accumulator

__device__ __forceinline__ unsigned short bf16_rne(float f) {
    unsigned u = __float_as_uint(f);
    u += 0x7FFFu + ((u >> 16) & 1u);
    return (unsigned short)(u >> 16);
}
__device__ __forceinline__ float bf16f(unsigned short h) {
    return __uint_as_float(((unsigned)h) << 16);
}

// ---------------- prep_w: conv_w [o][c][9] fp32 -> Ahi/Alo [r][o][c] bf16 (RNE) ----------
// Thread t of block o owns c = t*8..t*8+7: reads 72 contiguous fp32 (16B-aligned since
// (o*2048+t*8)*9*4 = 288*m), writes 9 r-planes as one 16B store each per plane.
__global__ __launch_bounds__(256) void prep_w(const float* __restrict__ w,
                                              unsigned short* __restrict__ Ahi,
                                              unsigned short* __restrict__ Alo) {
    int o = blockIdx.x, t = threadIdx.x;
    const float4* s4 = (const float4*)(w + ((size_t)o * 2048 + t * 8) * 9);
    float4 buf[18];
#pragma unroll
    for (int j = 0; j < 18; ++j) buf[j] = s4[j];
    const float* bf = (const float*)buf;   // bf[c*9 + r], c in 0..7
#pragma unroll
    for (int r = 0; r < 9; ++r) {
        unsigned short hs[8], ls[8];
#pragma unroll
        for (int c = 0; c < 8; ++c) {
            float x = bf[c * 9 + r];
            unsigned short h = bf16_rne(x);
            hs[c] = h;
            ls[c] = bf16_rne(x - bf16f(h));
        }
        size_t base = ((size_t)r * 2048 + o) * 2048 + t * 8;
        *(uint4*)(Ahi + base) = *(const uint4*)hs;
        *(uint4*)(Alo + base) = *(const uint4*)ls;
    }
}

// ---------------- prep_x: x [c][784] fp32 -> Xhi/Xlo [q=30x30 padded][c] bf16 (RNE) ------
__global__ __launch_bounds__(256) void prep_x(const float* __restrict__ x,
                                              unsigned short* __restrict__ Xhi,
                                              unsigned short* __restrict__ Xlo) {
    __shared__ float t[64][65];
    int c0 = blockIdx.x * 64, p0 = blockIdx.y * 64;
    int l = threadIdx.x & 63, g = threadIdx.x >> 6;
#pragma unroll
    for (int j = 0; j < 16; ++j) {
        int cl = j * 4 + g;
        int p = p0 + l;
        t[cl][l] = (p < 784) ? x[(size_t)(c0 + cl) * 784 + p] : 0.f;
    }
    __syncthreads();
#pragma unroll
    for (int j = 0; j < 16; ++j) {
        int pl = j * 4 + g;
        int p = p0 + pl;
        if (p < 784) {
            int q = (p / 28 + 1) * 30 + (p % 28) + 1;  // interior of zero-padded 30x30
            float v = t[l][pl];
            unsigned short hi = bf16_rne(v);
            unsigned short lo = bf16_rne(v - bf16f(hi));
            Xhi[(size_t)q * 2048 + c0 + l] = hi;
            Xlo[(size_t)q * 2048 + c0 + l] = lo;
        }
    }
}

// ---------------- conv implicit GEMM, r-split z=9; ALL staging via glds (no cvt VALU) ----
#define AHI_OFF 0
#define ALO_OFF 8192
#define BHI_OFF 16384
#define BLO_OFF 23552
#define LDS_BYTES 30720
#define NSTEP 64          // K chunk = 2048 per r

__global__ __launch_bounds__(256, 4) void conv_gemm(const char* __restrict__ wsb,
                                                    uint32_t offAhi, uint32_t offAlo,
                                                    uint32_t offXhi, uint32_t offXlo,
                                                    float* __restrict__ part) {
    __shared__ char smem[LDS_BYTES];
    int tid = threadIdx.x;
    int lane = tid & 63, wave = tid >> 6;
    int bm0 = blockIdx.x * 128, bn0 = blockIdx.y * 112, r = blockIdx.z;
    int offr = (r / 3 - 1) * 30 + (r % 3 - 1);

    // 32 glds slots: 30 real (8 Ahi + 8 Alo + 7 Bhi + 7 Blo) + 2 benign dups (r7 pattern).
    uint32_t doff[8], dlds[8];
#pragma unroll
    for (int j = 0; j < 8; ++j) {
        int i = wave + 4 * j;           // 0..31
        if (i >= 30) i -= 2;            // dup of B-lo tiles 5,6 (same src+dst: benign)
        int rowq = lane >> 2, pos = lane & 3;
        uint32_t gbyte, lofs;
        if (i < 16) {  // A tiles: 16 rows x 64B per instr
            int jj = i & 7;
            int row = jj * 16 + rowq;
            int gblk = pos ^ ((row >> 1) & 3);         // XOR swizzle @16B blocks
            uint32_t elem = ((uint32_t)r << 22) + (uint32_t)(bm0 + row) * 2048 + gblk * 8;
            gbyte = ((i < 8) ? offAhi : offAlo) + elem * 2;
            lofs = ((i < 8) ? AHI_OFF : ALO_OFF) + jj * 1024;
        } else {       // B tiles from padded image
            int jj = (i - 16) % 7;
            bool hiP = i < 23;
            int prow = jj * 16 + rowq;
            int p = bn0 + prow;
            int q = (p / 28 + 1) * 30 + (p % 28) + 1 + offr;  // border zeros handle taps
            int gblk = pos ^ ((prow >> 1) & 3);
            uint32_t elem = (uint32_t)q * 2048 + gblk * 8;
            gbyte = (hiP ? offXhi : offXlo) + elem * 2;
            lofs = (hiP ? BHI_OFF : BLO_OFF) + jj * 1024;
        }
        doff[j] = gbyte;
        dlds[j] = lofs;
    }

    int m = lane & 15, qd = lane >> 4;
    int sw = (m >> 1) & 3;
    uint32_t apos = (uint32_t)(wave * 32 + m) * 64 + (uint32_t)((qd ^ sw) * 16);
    uint32_t bpos = (uint32_t)m * 64 + (uint32_t)((qd ^ sw) * 16);

    f4v acc[2][7];
#pragma unroll
    for (int a = 0; a < 2; ++a)
#pragma unroll
        for (int b = 0; b < 7; ++b) acc[a][b] = f4v{0.f, 0.f, 0.f, 0.f};

    for (int step = 0; step < NSTEP; ++step) {
#pragma unroll
        for (int j = 0; j < 8; ++j) {
            __builtin_amdgcn_global_load_lds(
                (const __attribute__((address_space(1))) void*)(wsb + doff[j]),
                (__attribute__((address_space(3))) void*)(smem + dlds[j]), 16, 0, 0);
            doff[j] += 64;  // advance 32 bf16 along c
        }
        __syncthreads();

        s8v ah[2], al[2];
#pragma unroll
        for (int mt = 0; mt < 2; ++mt) {
            ah[mt] = *(const s8v*)(smem + AHI_OFF + apos + mt * 1024);
            al[mt] = *(const s8v*)(smem + ALO_OFF + apos + mt * 1024);
        }
#pragma unroll
        for (int nt = 0; nt < 7; ++nt) {
            s8v bh = *(const s8v*)(smem + BHI_OFF + bpos + nt * 1024);
            s8v bl = *(const s8v*)(smem + BLO_OFF + bpos + nt * 1024);
#pragma unroll
            for (int mt = 0; mt < 2; ++mt) {
                acc[mt][nt] = __builtin_amdgcn_mfma_f32_16x16x32_bf16(ah[mt], bh, acc[mt][nt], 0, 0, 0);
                acc[mt][nt] = __builtin_amdgcn_mfma_f32_16x16x32_bf16(ah[mt], bl, acc[mt][nt], 0, 0, 0);
                acc[mt][nt] = __builtin_amdgcn_mfma_f32_16x16x32_bf16(al[mt], bh, acc[mt][nt], 0, 0, 0);
            }
        }
        __syncthreads();
    }

    // epilogue: C row(o)=qd*4+reg, col(p)=m; accumulate the 9 r-partials via atomics
#pragma unroll
    for (int mt = 0; mt < 2; ++mt) {
        int o = bm0 + wave * 32 + mt * 16 + qd * 4;
#pragma unroll
        for (int nt = 0; nt < 7; ++nt) {
            int p = bn0 + nt * 16 + m;
            float* hp = part + (size_t)p * 2048 + o;
            atomicAdd(hp + 0, acc[mt][nt].x);
            atomicAdd(hp + 1, acc[mt][nt].y);
            atomicAdd(hp + 2, acc[mt][nt].z);
            atomicAdd(hp + 3, acc[mt][nt].w);
        }
    }
}

// ---------------- heads: block per pixel; bias+ReLU, 45 dots, sigmoid, exact scatter -----
__constant__ int HMIN_d[9] = {3, 2, 1, 6, 4, 3, 11, 8, 6};
__constant__ int WMIN_d[9] = {1, 2, 3, 3, 4, 6, 6, 8, 11};

__global__ __launch_bounds__(256) void heads(const float* __restrict__ hbuf,
                                             const float* __restrict__ conv_b,
                                             const float* __restrict__ reg_w,
                                             const float* __restrict__ reg_b,
                                             const float* __restrict__ cls_w,
                                             const float* __restrict__ cls_b,
                                             float* __restrict__ out) {
    int tid = threadIdx.x;
    int lane = tid & 63, wave = tid >> 6;
    int p = blockIdx.x;                 // source pixel p'
    int ci = tid * 2;                   // float4-pair index: channels [tid*8, tid*8+8)

    const float4* hp = (const float4*)(hbuf + (size_t)p * 2048);
    float4 h0 = hp[ci], h1 = hp[ci + 1];
    float4 b0 = ((const float4*)conv_b)[ci], b1 = ((const float4*)conv_b)[ci + 1];
    h0.x = fmaxf(h0.x + b0.x, 0.f); h0.y = fmaxf(h0.y + b0.y, 0.f);
    h0.z = fmaxf(h0.z + b0.z, 0.f); h0.w = fmaxf(h0.w + b0.w, 0.f);
    h1.x = fmaxf(h1.x + b1.x, 0.f); h1.y = fmaxf(h1.y + b1.y, 0.f);
    h1.z = fmaxf(h1.z + b1.z, 0.f); h1.w = fmaxf(h1.w + b1.w, 0.f);

    float s[45];
#pragma unroll
    for (int o = 0; o < 36; ++o) {
        float4 wa = ((const float4*)(reg_w + (size_t)o * 2048))[ci];
        float4 wb = ((const float4*)(reg_w + (size_t)o * 2048))[ci + 1];
        s[o] = h0.x * wa.x + h0.y * wa.y + h0.z * wa.z + h0.w * wa.w +
               h1.x * wb.x + h1.y * wb.y + h1.z * wb.z + h1.w * wb.w;
    }
#pragma unroll
    for (int a = 0; a < 9; ++a) {
        float4 wa = ((const float4*)(cls_w + (size_t)a * 2048))[ci];
        float4 wb = ((const float4*)(cls_w + (size_t)a * 2048))[ci + 1];
        s[36 + a] = h0.x * wa.x + h0.y * wa.y + h0.z * wa.z + h0.w * wa.w +
                    h1.x * wb.x + h1.y * wb.y + h1.z * wb.z + h1.w * wb.w;
    }

    __shared__ float wsum[4][45];
    __shared__ float fin[45];
#pragma unroll
    for (int o = 0; o < 45; ++o) {
        float v = s[o];
#pragma unroll
        for (int d = 1; d < 64; d <<= 1) v += __shfl_xor(v, d, 64);
        if (lane == 0) wsum[wave][o] = v;
    }
    __syncthreads();
    if (tid < 45) fin[tid] = wsum[0][tid] + wsum[1][tid] + wsum[2][tid] + wsum[3][tid];
    __syncthreads();

    // Reference view-chain: valid set over n = pix*9 + a (geometry); data at row n from
    // channel a' = n//784, pixel p' = n%784. This block owns p'; n = a'*784 + p'.
    if (tid < 9) {
        int ap = tid;
        int n = ap * 784 + p;
        int pix = n / 9, a2 = n % 9;
        int hh = pix / 28, ww = pix % 28;
        if (hh >= HMIN_d[a2] && ww >= WMIN_d[a2]) {
            int row = 0;
#pragma unroll
            for (int a3 = 0; a3 < 9; ++a3) {
                int hm = HMIN_d[a3], wm = WMIN_d[a3];
                int full = hh - hm; if (full < 0) full = 0;
                row += full * (28 - wm);
                if (hh >= hm) { int prt = ww - wm; if (prt < 0) prt = 0; row += prt; }
                if (a3 < a2 && hh >= hm && ww >= wm) row += 1;
            }
            float cl = fin[36 + ap] + cls_b[ap];
            float keep = (1.f / (1.f + expf(-cl)) > 0.9f) ? 1.f : 0.f;
#pragma unroll
            for (int q = 0; q < 4; ++q) {
                float rl = fin[q * 9 + ap] + reg_b[q * 9 + ap];
                out[row * 4 + q] = keep / (1.f + expf(-rl));
            }
        }
    }
}

extern "C" void kernel_launch(void* const* d_in, const int* in_sizes, int n_in,
                              void* d_out, int out_size, void* d_ws, size_t ws_size,
                              hipStream_t stream) {
    const float* x = (const float*)d_in[0];
    const float* conv_w = (const float*)d_in[1];
    const float* conv_b = (const float*)d_in[2];
    const float* reg_w = (const float*)d_in[3];
    const float* reg_b = (const float*)d_in[4];
    const float* cls_w = (const float*)d_in[5];
    const float* cls_b = (const float*)d_in[6];
    float* out = (float*)d_out;
    char* ws = (char*)d_ws;

    // workspace layout (bytes) — total 164,790,272 (exactly r2's proven-safe size)
    const size_t o_part = 0;         // fp32 conv accumulator [784][2048] : 6,422,528
    const size_t o_Xhi = 6422528;    // bf16 [900][2048]                   : 3,686,400
    const size_t o_Xlo = 10108928;   // bf16 [900][2048]                   : 3,686,400
    const size_t o_Ahi = 13795328;   // bf16 [9][2048][2048]               : 75,497,472
    const size_t o_Alo = 89292800;   // bf16 [9][2048][2048]               : 75,497,472

    hipMemsetAsync(ws + o_part, 0, 13795328, stream);  // part zeros + X-plane borders

    prep_x<<<dim3(32, 13), 256, 0, stream>>>(x, (unsigned short*)(ws + o_Xhi),
                                             (unsigned short*)(ws + o_Xlo));
    prep_w<<<2048, 256, 0, stream>>>(conv_w, (unsigned short*)(ws + o_Ahi),
                                     (unsigned short*)(ws + o_Alo));
    conv_gemm<<<dim3(16, 7, 9), 256, 0, stream>>>(ws, (uint32_t)o_Ahi, (uint32_t)o_Alo,
                                                  (uint32_t)o_Xhi, (uint32_t)o_Xlo,
                                                  (float*)(ws + o_part));
    heads<<<784, 256, 0, stream>>>((const float*)(ws + o_part), conv_b, reg_w, reg_b,
                                   cls_w, cls_b, out);
}